// Round 5
// baseline (370.081 us; speedup 1.0000x reference)
//
#include <hip/hip_runtime.h>

// SSIM3D, (4,1,128,128,128) fp32, separable 11-tap Gaussian, scalar mean out.
//
//  A: x-conv + y-conv fused, sliding-window accs over y. NO LDS, NO barriers:
//     x-window served by overlapping global float2 loads (L1-cached),
//     even-aligned via per-parity shifted 14-tap weights.
//  B: z-conv + SSIM map + reduction, sliding-window accs over z. Barrier-free
//     streaming; batches reversed so A's freshest output is L3-resident.
//  C: final reduce.
//
// R2-R4 lesson: every phase/barrier staging variant pinned at ~3 TB/s
// (drain stalls phase-lock all resident blocks). This round: zero barriers.

#define SLICE (128*128)        // 16384
#define S  (128*SLICE)         // 2097152 per field per batch
#define C1_ 0.0001f
#define C2_ 0.0009f

__device__ __forceinline__ void make_g(float* g) {
    float s = 0.f;
#pragma unroll
    for (int i = 0; i < 11; ++i) {
        float d = (float)(i - 5);
        g[i] = __expf(-d * d / 4.5f);
        s += g[i];
    }
    float inv = 1.f / s;
#pragma unroll
    for (int i = 0; i < 11; ++i) g[i] *= inv;
}

// ---------------- Kernel A: x-conv + y-conv, walk y ----------------
// grid: 4n * 128z * 4yc = 2048 blocks of 128 threads (2 waves), 16 waves/CU.
// Thread owns x = tid; walks 32 y outputs (42 input steps, slots mod 11).
// x-window cols [x-5, x+5] via 7 aligned float2 loads at even cols
// s0-6+2m (s0 = x&~1), weights w14[j] (j=0..13, col=s0-6+j):
//   tap k of g satisfies col = x+k-5 -> j = k+1+odd; out-of-range -> 0.
__global__ __launch_bounds__(128, 4)
void ssimA(const float* __restrict__ img1, const float* __restrict__ img2,
           float* __restrict__ fields) {
    float g[11]; make_g(g);
    const int x = threadIdx.x;               // 0..127
    const int odd = x & 1;
    const int s0 = x & ~1;
    const int b = blockIdx.x;
    const int yc = b & 3, z = (b >> 2) & 127, n = b >> 9;
    const int y0 = yc * 32;
    const float* p1 = img1 + (size_t)n * S + (size_t)z * SLICE;
    const float* p2 = img2 + (size_t)n * S + (size_t)z * SLICE;
    float* fb = fields + (size_t)n * 5 * S + (size_t)z * SLICE + x;

    // per-parity shifted taps, boundary-zeroed (static g indices only)
    float w14[14];
#pragma unroll
    for (int j = 0; j < 14; ++j) {
        int c = s0 - 6 + j;
        bool cok = (c >= 0) && (c < 128);
        float we = (j >= 1 && j <= 11 && cok) ? g[j - 1] : 0.f;  // even x
        float wo = (j >= 2 && j <= 12 && cok) ? g[j - 2] : 0.f;  // odd x
        w14[j] = odd ? wo : we;
    }
    // clamped even base offsets (address safety; clamped taps have w=0)
    int cc[7];
#pragma unroll
    for (int m = 0; m < 7; ++m)
        cc[m] = min(max(s0 - 6 + 2 * m, 0), 126);

    float acc[5][11];
#pragma unroll
    for (int f = 0; f < 5; ++f)
#pragma unroll
        for (int s2 = 0; s2 < 11; ++s2) acc[f][s2] = 0.f;

#pragma unroll 1
    for (int blk = 0; blk < 4; ++blk) {
#pragma unroll
        for (int t = 0; t < 11; ++t) {
            int step = blk * 11 + t;
            if (step >= 42) continue;            // wave-uniform (last 2)
            int y_in = y0 + step - 5;
            int ycl = min(max(y_in, 0), 127);
            bool row_ok = (y_in >= 0) && (y_in < 128);
            size_t ro = (size_t)ycl * 128;

            float u1 = 0, u2 = 0, a11 = 0, a22 = 0, a12 = 0;
#pragma unroll
            for (int m = 0; m < 7; ++m) {
                float2 A2 = *(const float2*)(p1 + ro + cc[m]);
                float2 B2 = *(const float2*)(p2 + ro + cc[m]);
                {
                    float wj = w14[2 * m];
                    float ta = wj * A2.x, tb = wj * B2.x;
                    u1 += ta; u2 += tb;
                    a11 = fmaf(ta, A2.x, a11);
                    a12 = fmaf(ta, B2.x, a12);
                    a22 = fmaf(tb, B2.x, a22);
                }
                {
                    float wj = w14[2 * m + 1];
                    float ta = wj * A2.y, tb = wj * B2.y;
                    u1 += ta; u2 += tb;
                    a11 = fmaf(ta, A2.y, a11);
                    a12 = fmaf(ta, B2.y, a12);
                    a22 = fmaf(tb, B2.y, a22);
                }
            }
            // y-accumulate: slot (t+j+1)%11 static under the unroll
#pragma unroll
            for (int j = 0; j < 11; ++j) {
                int oo = step - 10 + j;
                float wy = (row_ok && oo >= 0 && oo < 32) ? g[10 - j] : 0.f;
                const int sl = (t + j + 1) % 11;
                acc[0][sl] = fmaf(wy, u1,  acc[0][sl]);
                acc[1][sl] = fmaf(wy, u2,  acc[1][sl]);
                acc[2][sl] = fmaf(wy, a11, acc[2][sl]);
                acc[3][sl] = fmaf(wy, a22, acc[3][sl]);
                acc[4][sl] = fmaf(wy, a12, acc[4][sl]);
            }
            if (step >= 10) {
                const int es = (t + 1) % 11;     // static
                size_t wo_ = (size_t)(y0 + step - 10) * 128;
#pragma unroll
                for (int f = 0; f < 5; ++f) {
                    fb[(size_t)f * S + wo_] = acc[f][es];
                    acc[f][es] = 0.f;
                }
            }
        }
    }
}

// ---------------- Kernel B: z-conv + map + reduce, walk z ----------------
// grid: 4n * 64y2 * 4zc = 1024 blocks of 256 threads (4 waves), 16 waves/CU.
// Thread owns (x = tid&127, y = 2*y2 + (tid>>7)); walks 32 z outputs.
// Batches in REVERSE (freshest A output first -> L3 hits). No barriers
// until the tiny end-of-kernel reduction.
__global__ __launch_bounds__(256, 4)
void ssimB(const float* __restrict__ fields, float* __restrict__ partials) {
    float g[11]; make_g(g);
    const int tid = threadIdx.x;
    const int x = tid & 127, yr = tid >> 7;
    const int b = blockIdx.x;
    const int zc = b & 3, y2 = (b >> 2) & 63;
    const int n = 3 - (b >> 8);
    const int y = y2 * 2 + yr;
    const int z0 = zc * 32;
    const float* base = fields + (size_t)n * 5 * S + (size_t)y * 128 + x;

    float acc[5][11];
#pragma unroll
    for (int f = 0; f < 5; ++f)
#pragma unroll
        for (int s2 = 0; s2 < 11; ++s2) acc[f][s2] = 0.f;

    float sum = 0.f;

#pragma unroll 1
    for (int blk = 0; blk < 4; ++blk) {
#pragma unroll
        for (int t = 0; t < 11; ++t) {
            int step = blk * 11 + t;
            if (step >= 42) continue;            // wave-uniform
            int z_in = z0 + step - 5;
            int zcl = min(max(z_in, 0), 127);
            bool row_ok = (z_in >= 0) && (z_in < 128);
            size_t off = (size_t)zcl * SLICE;
            float f0 = base[0 * (size_t)S + off];
            float f1 = base[1 * (size_t)S + off];
            float f2 = base[2 * (size_t)S + off];
            float f3 = base[3 * (size_t)S + off];
            float f4 = base[4 * (size_t)S + off];
#pragma unroll
            for (int j = 0; j < 11; ++j) {
                int oo = step - 10 + j;
                float wz = (row_ok && oo >= 0 && oo < 32) ? g[10 - j] : 0.f;
                const int sl = (t + j + 1) % 11;
                acc[0][sl] = fmaf(wz, f0, acc[0][sl]);
                acc[1][sl] = fmaf(wz, f1, acc[1][sl]);
                acc[2][sl] = fmaf(wz, f2, acc[2][sl]);
                acc[3][sl] = fmaf(wz, f3, acc[3][sl]);
                acc[4][sl] = fmaf(wz, f4, acc[4][sl]);
            }
            if (step >= 10) {
                const int es = (t + 1) % 11;     // static
                float m1 = acc[0][es], m2 = acc[1][es];
                float p11 = acc[2][es], p22 = acc[3][es];
                float p12 = acc[4][es];
                float m1s = m1 * m1, m2s = m2 * m2, m12 = m1 * m2;
                float v1 = p11 - m1s, v2 = p22 - m2s, cv = p12 - m12;
                float num = (2.f * m12 + C1_) * (2.f * cv + C2_);
                float den = (m1s + m2s + C1_) * (v1 + v2 + C2_);
                sum += num / den;
#pragma unroll
                for (int f = 0; f < 5; ++f) acc[f][es] = 0.f;
            }
        }
    }
    // 4-wave reduce
#pragma unroll
    for (int o = 32; o > 0; o >>= 1) sum += __shfl_down(sum, o, 64);
    __shared__ float ws4[4];
    if ((tid & 63) == 0) ws4[tid >> 6] = sum;
    __syncthreads();
    if (tid == 0) partials[blockIdx.x] = ws4[0] + ws4[1] + ws4[2] + ws4[3];
}

// ---------------- final reduce ----------------
__global__ void ssim_final(const float* __restrict__ partial, int n,
                           float* __restrict__ out, double inv_count) {
    int tid = threadIdx.x;
    double s = 0.0;
    for (int i = tid; i < n; i += 256) s += (double)partial[i];
#pragma unroll
    for (int o = 32; o > 0; o >>= 1) s += __shfl_down(s, o, 64);
    __shared__ double wsum[4];
    int lane = tid & 63, wid = tid >> 6;
    if (lane == 0) wsum[wid] = s;
    __syncthreads();
    if (tid == 0)
        out[0] = (float)((wsum[0] + wsum[1] + wsum[2] + wsum[3]) * inv_count);
}

extern "C" void kernel_launch(void* const* d_in, const int* in_sizes, int n_in,
                              void* d_out, int out_size, void* d_ws, size_t ws_size,
                              hipStream_t stream) {
    const float* img1 = (const float*)d_in[0];
    const float* img2 = (const float*)d_in[1];
    float* out = (float*)d_out;

    float* fields   = (float*)d_ws;                    // 20*S floats (167.8 MB)
    float* partials = fields + 20 * (size_t)S;         // 1024 floats

    ssimA<<<2048, 128, 0, stream>>>(img1, img2, fields);
    ssimB<<<1024, 256, 0, stream>>>(fields, partials);
    ssim_final<<<1, 256, 0, stream>>>(partials, 1024, out,
                                      1.0 / ((double)S * 4));
}

// Round 6
// 257.086 us; speedup vs baseline: 1.4395x; 1.4395x over previous
//
#include <hip/hip_runtime.h>

// SSIM3D, (4,1,128,128,128) fp32, separable 11-tap Gaussian, scalar mean out.
//
//  A: x-conv + y-conv fused, sliding-window accs over y. Barrier-free,
//     overlapping global float2 loads, explicit 1-step prefetch.
//  B: z-conv + SSIM map + reduction, sliding-window accs over z, explicit
//     1-step prefetch; batches reversed so A's output is L3-resident.
//  C: final reduce.
//
// R3-R5 lesson: allocator picked 64 VGPR (occupancy heuristic) for a ~120-reg
// live set -> serialized MLP, waves 96% stalled, ~2-3 TB/s ceiling. Fix:
// __launch_bounds__(..., 2) => 256-VGPR budget + explicit prefetch pipeline.

#define SLICE (128*128)        // 16384
#define S  (128*SLICE)         // 2097152 per field per batch
#define C1_ 0.0001f
#define C2_ 0.0009f

__device__ __forceinline__ void make_g(float* g) {
    float s = 0.f;
#pragma unroll
    for (int i = 0; i < 11; ++i) {
        float d = (float)(i - 5);
        g[i] = __expf(-d * d / 4.5f);
        s += g[i];
    }
    float inv = 1.f / s;
#pragma unroll
    for (int i = 0; i < 11; ++i) g[i] *= inv;
}

// ---------------- Kernel A: x-conv + y-conv, walk y ----------------
// grid: 4n * 128z * 4yc = 2048 blocks of 128 threads (2 waves).
// Thread owns x = tid; walks 32 y outputs (42 input steps, slots mod 11).
// x-window [x-5,x+5] via 7 aligned float2 loads at even cols s0-6+2m
// (s0 = x&~1); per-parity shifted weights w14 (boundary taps zeroed).
__global__ __launch_bounds__(128, 2)
void ssimA(const float* __restrict__ img1, const float* __restrict__ img2,
           float* __restrict__ fields) {
    float g[11]; make_g(g);
    const int x = threadIdx.x;               // 0..127
    const int odd = x & 1;
    const int s0 = x & ~1;
    const int b = blockIdx.x;
    const int yc = b & 3, z = (b >> 2) & 127, n = b >> 9;
    const int y0 = yc * 32;
    const float* p1 = img1 + (size_t)n * S + (size_t)z * SLICE;
    const float* p2 = img2 + (size_t)n * S + (size_t)z * SLICE;
    float* fb = fields + (size_t)n * 5 * S + (size_t)z * SLICE + x;

    // per-parity shifted taps, boundary-zeroed (static g indices only)
    float w14[14];
#pragma unroll
    for (int j = 0; j < 14; ++j) {
        int c = s0 - 6 + j;
        bool cok = (c >= 0) && (c < 128);
        float we = (j >= 1 && j <= 11 && cok) ? g[j - 1] : 0.f;  // even x
        float wo = (j >= 2 && j <= 12 && cok) ? g[j - 2] : 0.f;  // odd x
        w14[j] = odd ? wo : we;
    }
    // clamped even base offsets (clamped taps carry zero weight)
    int cc[7];
#pragma unroll
    for (int m = 0; m < 7; ++m)
        cc[m] = min(max(s0 - 6 + 2 * m, 0), 126);

    float acc[5][11];
#pragma unroll
    for (int f = 0; f < 5; ++f)
#pragma unroll
        for (int s2 = 0; s2 < 11; ++s2) acc[f][s2] = 0.f;

    // prefetch pipeline registers
    float2 Pa[7], Pb[7];
    {
        int ycl = min(max(y0 - 5, 0), 127);   // step 0
        size_t ro = (size_t)ycl * 128;
#pragma unroll
        for (int m = 0; m < 7; ++m) {
            Pa[m] = *(const float2*)(p1 + ro + cc[m]);
            Pb[m] = *(const float2*)(p2 + ro + cc[m]);
        }
    }

#pragma unroll 1
    for (int blk = 0; blk < 4; ++blk) {
#pragma unroll
        for (int t = 0; t < 11; ++t) {
            int step = blk * 11 + t;
            if (step >= 42) continue;            // wave-uniform (last 2)

            // consume current, issue next (SSA under full unroll)
            float2 Ca[7], Cb[7];
#pragma unroll
            for (int m = 0; m < 7; ++m) { Ca[m] = Pa[m]; Cb[m] = Pb[m]; }
            if (step + 1 < 42) {
                int ycl = min(max(y0 + step + 1 - 5, 0), 127);
                size_t ro = (size_t)ycl * 128;
#pragma unroll
                for (int m = 0; m < 7; ++m) {
                    Pa[m] = *(const float2*)(p1 + ro + cc[m]);
                    Pb[m] = *(const float2*)(p2 + ro + cc[m]);
                }
            }

            int y_in = y0 + step - 5;
            bool row_ok = (y_in >= 0) && (y_in < 128);

            float u1 = 0, u2 = 0, a11 = 0, a22 = 0, a12 = 0;
#pragma unroll
            for (int m = 0; m < 7; ++m) {
                {
                    float wj = w14[2 * m];
                    float ta = wj * Ca[m].x, tb = wj * Cb[m].x;
                    u1 += ta; u2 += tb;
                    a11 = fmaf(ta, Ca[m].x, a11);
                    a12 = fmaf(ta, Cb[m].x, a12);
                    a22 = fmaf(tb, Cb[m].x, a22);
                }
                {
                    float wj = w14[2 * m + 1];
                    float ta = wj * Ca[m].y, tb = wj * Cb[m].y;
                    u1 += ta; u2 += tb;
                    a11 = fmaf(ta, Ca[m].y, a11);
                    a12 = fmaf(ta, Cb[m].y, a12);
                    a22 = fmaf(tb, Cb[m].y, a22);
                }
            }
            // y-accumulate: slot (t+j+1)%11 static under the unroll
#pragma unroll
            for (int j = 0; j < 11; ++j) {
                int oo = step - 10 + j;
                float wy = (row_ok && oo >= 0 && oo < 32) ? g[10 - j] : 0.f;
                const int sl = (t + j + 1) % 11;
                acc[0][sl] = fmaf(wy, u1,  acc[0][sl]);
                acc[1][sl] = fmaf(wy, u2,  acc[1][sl]);
                acc[2][sl] = fmaf(wy, a11, acc[2][sl]);
                acc[3][sl] = fmaf(wy, a22, acc[3][sl]);
                acc[4][sl] = fmaf(wy, a12, acc[4][sl]);
            }
            if (step >= 10) {
                const int es = (t + 1) % 11;     // static
                size_t wo_ = (size_t)(y0 + step - 10) * 128;
#pragma unroll
                for (int f = 0; f < 5; ++f) {
                    fb[(size_t)f * S + wo_] = acc[f][es];
                    acc[f][es] = 0.f;
                }
            }
        }
    }
}

// ---------------- Kernel B: z-conv + map + reduce, walk z ----------------
// grid: 4n * 64y2 * 4zc = 1024 blocks of 256 threads (4 waves).
// Thread owns (x = tid&127, y = 2*y2 + (tid>>7)); walks 32 z outputs.
// Batches in REVERSE (freshest A output first -> L3 hits).
__global__ __launch_bounds__(256, 2)
void ssimB(const float* __restrict__ fields, float* __restrict__ partials) {
    float g[11]; make_g(g);
    const int tid = threadIdx.x;
    const int x = tid & 127, yr = tid >> 7;
    const int b = blockIdx.x;
    const int zc = b & 3, y2 = (b >> 2) & 63;
    const int n = 3 - (b >> 8);
    const int y = y2 * 2 + yr;
    const int z0 = zc * 32;
    const float* base = fields + (size_t)n * 5 * S + (size_t)y * 128 + x;

    float acc[5][11];
#pragma unroll
    for (int f = 0; f < 5; ++f)
#pragma unroll
        for (int s2 = 0; s2 < 11; ++s2) acc[f][s2] = 0.f;

    float sum = 0.f;

    // prefetch pipeline
    float P[5];
    {
        size_t off = (size_t)min(max(z0 - 5, 0), 127) * SLICE;
#pragma unroll
        for (int f = 0; f < 5; ++f) P[f] = base[(size_t)f * S + off];
    }

#pragma unroll 1
    for (int blk = 0; blk < 4; ++blk) {
#pragma unroll
        for (int t = 0; t < 11; ++t) {
            int step = blk * 11 + t;
            if (step >= 42) continue;            // wave-uniform

            float C[5];
#pragma unroll
            for (int f = 0; f < 5; ++f) C[f] = P[f];
            if (step + 1 < 42) {
                size_t off = (size_t)min(max(z0 + step + 1 - 5, 0), 127) * SLICE;
#pragma unroll
                for (int f = 0; f < 5; ++f) P[f] = base[(size_t)f * S + off];
            }

            int z_in = z0 + step - 5;
            bool row_ok = (z_in >= 0) && (z_in < 128);
#pragma unroll
            for (int j = 0; j < 11; ++j) {
                int oo = step - 10 + j;
                float wz = (row_ok && oo >= 0 && oo < 32) ? g[10 - j] : 0.f;
                const int sl = (t + j + 1) % 11;
                acc[0][sl] = fmaf(wz, C[0], acc[0][sl]);
                acc[1][sl] = fmaf(wz, C[1], acc[1][sl]);
                acc[2][sl] = fmaf(wz, C[2], acc[2][sl]);
                acc[3][sl] = fmaf(wz, C[3], acc[3][sl]);
                acc[4][sl] = fmaf(wz, C[4], acc[4][sl]);
            }
            if (step >= 10) {
                const int es = (t + 1) % 11;     // static
                float m1 = acc[0][es], m2 = acc[1][es];
                float p11 = acc[2][es], p22 = acc[3][es];
                float p12 = acc[4][es];
                float m1s = m1 * m1, m2s = m2 * m2, m12 = m1 * m2;
                float v1 = p11 - m1s, v2 = p22 - m2s, cv = p12 - m12;
                float num = (2.f * m12 + C1_) * (2.f * cv + C2_);
                float den = (m1s + m2s + C1_) * (v1 + v2 + C2_);
                sum += num / den;
#pragma unroll
                for (int f = 0; f < 5; ++f) acc[f][es] = 0.f;
            }
        }
    }
    // 4-wave reduce
#pragma unroll
    for (int o = 32; o > 0; o >>= 1) sum += __shfl_down(sum, o, 64);
    __shared__ float ws4[4];
    if ((tid & 63) == 0) ws4[tid >> 6] = sum;
    __syncthreads();
    if (tid == 0) partials[blockIdx.x] = ws4[0] + ws4[1] + ws4[2] + ws4[3];
}

// ---------------- final reduce ----------------
__global__ void ssim_final(const float* __restrict__ partial, int n,
                           float* __restrict__ out, double inv_count) {
    int tid = threadIdx.x;
    double s = 0.0;
    for (int i = tid; i < n; i += 256) s += (double)partial[i];
#pragma unroll
    for (int o = 32; o > 0; o >>= 1) s += __shfl_down(s, o, 64);
    __shared__ double wsum[4];
    int lane = tid & 63, wid = tid >> 6;
    if (lane == 0) wsum[wid] = s;
    __syncthreads();
    if (tid == 0)
        out[0] = (float)((wsum[0] + wsum[1] + wsum[2] + wsum[3]) * inv_count);
}

extern "C" void kernel_launch(void* const* d_in, const int* in_sizes, int n_in,
                              void* d_out, int out_size, void* d_ws, size_t ws_size,
                              hipStream_t stream) {
    const float* img1 = (const float*)d_in[0];
    const float* img2 = (const float*)d_in[1];
    float* out = (float*)d_out;

    float* fields   = (float*)d_ws;                    // 20*S floats (167.8 MB)
    float* partials = fields + 20 * (size_t)S;         // 1024 floats

    ssimA<<<2048, 128, 0, stream>>>(img1, img2, fields);
    ssimB<<<1024, 256, 0, stream>>>(fields, partials);
    ssim_final<<<1, 256, 0, stream>>>(partials, 1024, out,
                                      1.0 / ((double)S * 4));
}

// Round 7
// 252.688 us; speedup vs baseline: 1.4646x; 1.0174x over previous
//
#include <hip/hip_runtime.h>

// SSIM3D, (4,1,128,128,128) fp32, separable 11-tap Gaussian, scalar mean out.
//
//  A: x-conv + y-conv fused, sliding-window accs over y. Barrier-free
//     overlapping global float2 loads; DEPTH-2 software prefetch (L3 latency
//     ~600cyc > 1-step cover -- R6's 70% stall).
//  B: z-conv + SSIM map + reduction, sliding-window accs over z; depth-2
//     prefetch; batches reversed so A's output is L3-resident.
//  C: final reduce.
//
// R6 post-mortem: VGPR fix landed (128, no spills, WRITE == logical) but
// VALUBusy 30% -> latency-exposed on L3. This round: pipeline depth 2.

#define SLICE (128*128)        // 16384
#define S  (128*SLICE)         // 2097152 per field per batch
#define C1_ 0.0001f
#define C2_ 0.0009f

__device__ __forceinline__ void make_g(float* g) {
    float s = 0.f;
#pragma unroll
    for (int i = 0; i < 11; ++i) {
        float d = (float)(i - 5);
        g[i] = __expf(-d * d / 4.5f);
        s += g[i];
    }
    float inv = 1.f / s;
#pragma unroll
    for (int i = 0; i < 11; ++i) g[i] *= inv;
}

// ---------------- Kernel A: x-conv + y-conv, walk y ----------------
// grid: 4n * 128z * 4yc = 2048 blocks of 128 threads (2 waves).
// Thread owns x = tid; walks 32 y outputs (42 input steps, slots mod 11).
// x-window [x-5,x+5] via 7 aligned float2 loads at even cols s0-6+2m
// (s0 = x&~1); per-parity shifted weights w14 (boundary taps zeroed).
__global__ __launch_bounds__(128, 2)
void ssimA(const float* __restrict__ img1, const float* __restrict__ img2,
           float* __restrict__ fields) {
    float g[11]; make_g(g);
    const int x = threadIdx.x;               // 0..127
    const int odd = x & 1;
    const int s0 = x & ~1;
    const int b = blockIdx.x;
    const int yc = b & 3, z = (b >> 2) & 127, n = b >> 9;
    const int y0 = yc * 32;
    const float* p1 = img1 + (size_t)n * S + (size_t)z * SLICE;
    const float* p2 = img2 + (size_t)n * S + (size_t)z * SLICE;
    float* fb = fields + (size_t)n * 5 * S + (size_t)z * SLICE + x;

    // per-parity shifted taps, boundary-zeroed (static g indices only)
    float w14[14];
#pragma unroll
    for (int j = 0; j < 14; ++j) {
        int c = s0 - 6 + j;
        bool cok = (c >= 0) && (c < 128);
        float we = (j >= 1 && j <= 11 && cok) ? g[j - 1] : 0.f;  // even x
        float wo = (j >= 2 && j <= 12 && cok) ? g[j - 2] : 0.f;  // odd x
        w14[j] = odd ? wo : we;
    }
    // clamped even base offsets (clamped taps carry zero weight)
    int cc[7];
#pragma unroll
    for (int m = 0; m < 7; ++m)
        cc[m] = min(max(s0 - 6 + 2 * m, 0), 126);

    float acc[5][11];
#pragma unroll
    for (int f = 0; f < 5; ++f)
#pragma unroll
        for (int s2 = 0; s2 < 11; ++s2) acc[f][s2] = 0.f;

    // depth-2 pipeline: P0 = data for current step, P1 = next step
    float2 A0[7], B0[7], A1[7], B1[7];
    {
        const float* r0a = p1 + (size_t)min(max(y0 - 5, 0), 127) * 128;
        const float* r0b = p2 + (size_t)min(max(y0 - 5, 0), 127) * 128;
        const float* r1a = p1 + (size_t)min(max(y0 - 4, 0), 127) * 128;
        const float* r1b = p2 + (size_t)min(max(y0 - 4, 0), 127) * 128;
#pragma unroll
        for (int m = 0; m < 7; ++m) {
            A0[m] = *(const float2*)(r0a + cc[m]);
            B0[m] = *(const float2*)(r0b + cc[m]);
            A1[m] = *(const float2*)(r1a + cc[m]);
            B1[m] = *(const float2*)(r1b + cc[m]);
        }
    }

#pragma unroll 1
    for (int blk = 0; blk < 4; ++blk) {
#pragma unroll
        for (int t = 0; t < 11; ++t) {
            int step = blk * 11 + t;
            if (step >= 42) continue;            // wave-uniform (last 2)

            // issue step+2 loads first (clamped at the tail: harmless re-read)
            int sp = min(step + 2, 41);
            int ycl = min(max(y0 + sp - 5, 0), 127);
            const float* ra = p1 + (size_t)ycl * 128;   // scalar row base
            const float* rb = p2 + (size_t)ycl * 128;
            float2 NA[7], NB[7];
#pragma unroll
            for (int m = 0; m < 7; ++m) {
                NA[m] = *(const float2*)(ra + cc[m]);
                NB[m] = *(const float2*)(rb + cc[m]);
            }

            int y_in = y0 + step - 5;
            bool row_ok = (y_in >= 0) && (y_in < 128);

            // consume current (A0/B0): x-conv of the 5 fields
            float u1 = 0, u2 = 0, a11 = 0, a22 = 0, a12 = 0;
#pragma unroll
            for (int m = 0; m < 7; ++m) {
                {
                    float wj = w14[2 * m];
                    float av = A0[m].x, bv = B0[m].x;
                    float ta = wj * av, tb = wj * bv;
                    u1 += ta; u2 += tb;
                    a11 = fmaf(ta, av, a11);
                    a12 = fmaf(ta, bv, a12);
                    a22 = fmaf(tb, bv, a22);
                }
                {
                    float wj = w14[2 * m + 1];
                    float av = A0[m].y, bv = B0[m].y;
                    float ta = wj * av, tb = wj * bv;
                    u1 += ta; u2 += tb;
                    a11 = fmaf(ta, av, a11);
                    a12 = fmaf(ta, bv, a12);
                    a22 = fmaf(tb, bv, a22);
                }
            }
            // y-accumulate: slot (t+j+1)%11 static under the unroll
#pragma unroll
            for (int j = 0; j < 11; ++j) {
                int oo = step - 10 + j;
                float wy = (row_ok && oo >= 0 && oo < 32) ? g[10 - j] : 0.f;
                const int sl = (t + j + 1) % 11;
                acc[0][sl] = fmaf(wy, u1,  acc[0][sl]);
                acc[1][sl] = fmaf(wy, u2,  acc[1][sl]);
                acc[2][sl] = fmaf(wy, a11, acc[2][sl]);
                acc[3][sl] = fmaf(wy, a22, acc[3][sl]);
                acc[4][sl] = fmaf(wy, a12, acc[4][sl]);
            }
            if (step >= 10) {
                const int es = (t + 1) % 11;     // static
                size_t wo_ = (size_t)(y0 + step - 10) * 128;
#pragma unroll
                for (int f = 0; f < 5; ++f) {
                    fb[(size_t)f * S + wo_] = acc[f][es];
                    acc[f][es] = 0.f;
                }
            }
            // rotate pipeline (SSA under the unroll; real moves only at blk edge)
#pragma unroll
            for (int m = 0; m < 7; ++m) {
                A0[m] = A1[m]; B0[m] = B1[m];
                A1[m] = NA[m]; B1[m] = NB[m];
            }
        }
    }
}

// ---------------- Kernel B: z-conv + map + reduce, walk z ----------------
// grid: 4n * 64y2 * 4zc = 1024 blocks of 256 threads (4 waves).
// Thread owns (x = tid&127, y = 2*y2 + (tid>>7)); walks 32 z outputs.
// Batches in REVERSE (freshest A output first -> L3 hits). Depth-2 prefetch.
__global__ __launch_bounds__(256, 4)
void ssimB(const float* __restrict__ fields, float* __restrict__ partials) {
    float g[11]; make_g(g);
    const int tid = threadIdx.x;
    const int x = tid & 127, yr = tid >> 7;
    const int b = blockIdx.x;
    const int zc = b & 3, y2 = (b >> 2) & 63;
    const int n = 3 - (b >> 8);
    const int y = y2 * 2 + yr;
    const int z0 = zc * 32;
    const float* base = fields + (size_t)n * 5 * S + (size_t)y * 128 + x;

    float acc[5][11];
#pragma unroll
    for (int f = 0; f < 5; ++f)
#pragma unroll
        for (int s2 = 0; s2 < 11; ++s2) acc[f][s2] = 0.f;

    float sum = 0.f;

    // depth-2 pipeline
    float P0[5], P1[5];
    {
        size_t o0 = (size_t)min(max(z0 - 5, 0), 127) * SLICE;
        size_t o1 = (size_t)min(max(z0 - 4, 0), 127) * SLICE;
#pragma unroll
        for (int f = 0; f < 5; ++f) {
            P0[f] = base[(size_t)f * S + o0];
            P1[f] = base[(size_t)f * S + o1];
        }
    }

#pragma unroll 1
    for (int blk = 0; blk < 4; ++blk) {
#pragma unroll
        for (int t = 0; t < 11; ++t) {
            int step = blk * 11 + t;
            if (step >= 42) continue;            // wave-uniform

            int sp = min(step + 2, 41);
            size_t off = (size_t)min(max(z0 + sp - 5, 0), 127) * SLICE;
            float N[5];
#pragma unroll
            for (int f = 0; f < 5; ++f) N[f] = base[(size_t)f * S + off];

            int z_in = z0 + step - 5;
            bool row_ok = (z_in >= 0) && (z_in < 128);
#pragma unroll
            for (int j = 0; j < 11; ++j) {
                int oo = step - 10 + j;
                float wz = (row_ok && oo >= 0 && oo < 32) ? g[10 - j] : 0.f;
                const int sl = (t + j + 1) % 11;
                acc[0][sl] = fmaf(wz, P0[0], acc[0][sl]);
                acc[1][sl] = fmaf(wz, P0[1], acc[1][sl]);
                acc[2][sl] = fmaf(wz, P0[2], acc[2][sl]);
                acc[3][sl] = fmaf(wz, P0[3], acc[3][sl]);
                acc[4][sl] = fmaf(wz, P0[4], acc[4][sl]);
            }
            if (step >= 10) {
                const int es = (t + 1) % 11;     // static
                float m1 = acc[0][es], m2 = acc[1][es];
                float p11 = acc[2][es], p22 = acc[3][es];
                float p12 = acc[4][es];
                float m1s = m1 * m1, m2s = m2 * m2, m12 = m1 * m2;
                float v1 = p11 - m1s, v2 = p22 - m2s, cv = p12 - m12;
                float num = (2.f * m12 + C1_) * (2.f * cv + C2_);
                float den = (m1s + m2s + C1_) * (v1 + v2 + C2_);
                sum += num / den;
#pragma unroll
                for (int f = 0; f < 5; ++f) acc[f][es] = 0.f;
            }
            // rotate
#pragma unroll
            for (int f = 0; f < 5; ++f) { P0[f] = P1[f]; P1[f] = N[f]; }
        }
    }
    // 4-wave reduce
#pragma unroll
    for (int o = 32; o > 0; o >>= 1) sum += __shfl_down(sum, o, 64);
    __shared__ float ws4[4];
    if ((tid & 63) == 0) ws4[tid >> 6] = sum;
    __syncthreads();
    if (tid == 0) partials[blockIdx.x] = ws4[0] + ws4[1] + ws4[2] + ws4[3];
}

// ---------------- final reduce ----------------
__global__ void ssim_final(const float* __restrict__ partial, int n,
                           float* __restrict__ out, double inv_count) {
    int tid = threadIdx.x;
    double s = 0.0;
    for (int i = tid; i < n; i += 256) s += (double)partial[i];
#pragma unroll
    for (int o = 32; o > 0; o >>= 1) s += __shfl_down(s, o, 64);
    __shared__ double wsum[4];
    int lane = tid & 63, wid = tid >> 6;
    if (lane == 0) wsum[wid] = s;
    __syncthreads();
    if (tid == 0)
        out[0] = (float)((wsum[0] + wsum[1] + wsum[2] + wsum[3]) * inv_count);
}

extern "C" void kernel_launch(void* const* d_in, const int* in_sizes, int n_in,
                              void* d_out, int out_size, void* d_ws, size_t ws_size,
                              hipStream_t stream) {
    const float* img1 = (const float*)d_in[0];
    const float* img2 = (const float*)d_in[1];
    float* out = (float*)d_out;

    float* fields   = (float*)d_ws;                    // 20*S floats (167.8 MB)
    float* partials = fields + 20 * (size_t)S;         // 1024 floats

    ssimA<<<2048, 128, 0, stream>>>(img1, img2, fields);
    ssimB<<<1024, 256, 0, stream>>>(fields, partials);
    ssim_final<<<1, 256, 0, stream>>>(partials, 1024, out,
                                      1.0 / ((double)S * 4));
}